// Round 6
// baseline (146.349 us; speedup 1.0000x reference)
//
#include <hip/hip_runtime.h>
#include <hip/hip_bf16.h>

// Problem constants
#define BATCH 2
#define TSEQ  2048
#define NEMBD 1024
#define HEADS 16
#define HDIM  64
// GEMM: M = BATCH*TSEQ = 4096, K = NEMBD = 1024, N = 3*NEMBD = 3072

typedef short          bf16x8 __attribute__((ext_vector_type(8)));  // 8 bf16 = 4 VGPRs
typedef float          f32x4  __attribute__((ext_vector_type(4)));
typedef unsigned short u16;

__device__ __forceinline__ u16 f2bf(float f) {
  unsigned int u = __float_as_uint(f);
  u += 0x7fffu + ((u >> 16) & 1u);   // round-to-nearest-even
  return (u16)(u >> 16);
}

// async global->LDS, 16B per lane; LDS dest = wave-uniform base + lane*16
__device__ __forceinline__ void gld16(const u16* g, u16* l) {
  __builtin_amdgcn_global_load_lds(
      (const __attribute__((address_space(1))) unsigned int*)g,
      (__attribute__((address_space(3))) unsigned int*)l, 16, 0, 0);
}

// raw barrier + scheduler fence: no implicit vmcnt(0) drain (unlike
// __syncthreads), and nothing (loads, DMA issues, MFMAs) crosses it.
#define BARSB() do { __builtin_amdgcn_s_barrier();      \
                     __builtin_amdgcn_sched_barrier(0); } while (0)

// ---------------------------------------------------------------------------
// Merged prep: blocks [0,4096) convert x fp32->bf16; blocks [4096,7168)
// transpose W [1024,3072] fp32 -> Wt [3072,1024] bf16 (32x32 LDS tiles).
__global__ __launch_bounds__(256) void k_prep(const float* __restrict__ x,
                                              u16* __restrict__ xb,
                                              const float* __restrict__ w,
                                              u16* __restrict__ wt) {
  __shared__ float tile[32][33];
  const int b = blockIdx.x;
  const int t = threadIdx.x;
  if (b < 4096) {
    int i = b * 256 + t;
    float4 v = ((const float4*)x)[i];
    ushort4 o;
    o.x = f2bf(v.x); o.y = f2bf(v.y); o.z = f2bf(v.z); o.w = f2bf(v.w);
    ((ushort4*)xb)[i] = o;
  } else {
    const int bt = b - 4096;            // 0..3071
    const int n0 = (bt >> 5) * 32;      // 0..3040
    const int k0 = (bt & 31) * 32;      // 0..992
    const int r  = t >> 3;              // 0..31
    const int c4 = (t & 7) * 4;         // 0,4,..,28
    float4 v = *(const float4*)(w + (size_t)(k0 + r) * 3072 + n0 + c4);
    tile[r][c4 + 0] = v.x; tile[r][c4 + 1] = v.y;
    tile[r][c4 + 2] = v.z; tile[r][c4 + 3] = v.w;
    __syncthreads();
    ushort4 o;
    o.x = f2bf(tile[c4 + 0][r]);
    o.y = f2bf(tile[c4 + 1][r]);
    o.z = f2bf(tile[c4 + 2][r]);
    o.w = f2bf(tile[c4 + 3][r]);
    *(ushort4*)(wt + (size_t)(n0 + r) * 1024 + k0 + c4) = o;
  }
}

// ---------------------------------------------------------------------------
// QKV GEMM v2: 256x256 tile, BK=64, 8 waves (2M x 4N), 512 threads,
// 128 KB double-buffered LDS, 4-phase/K-tile schedule with COUNTED vmcnt
// (never 0 in main loop) — T2+T3+T4+T5 per the verified 8-phase template.
//
// Staging halves are bit-interleaved so each phase's reads touch exactly one
// half for EVERY wave:  A-hs = rows with (row>>6)&1 == hs  (64-row granules),
//                       B-hs = rows with (row>>5)&1 == hs  (32-row granules).
// Phase p of K-tile kt (reads from buf kt&1, stages kt+1 into buf kt&1^1):
//   ph1: read A-hs0+B-hs0 (12 ds_read_b128), stage A-hs0', MFMA Q(0,0),
//        vmcnt(2) [retires A-hs1,B-hs1 of kt] before the post-MFMA barrier
//   ph2: read B-hs1 (4), stage B-hs0', MFMA Q(0,1)
//   ph3: read A-hs1 (8), stage A-hs1', MFMA Q(1,1)
//   ph4: stage B-hs1', MFMA Q(1,0),
//        vmcnt(4) [retires A-hs0',B-hs0'] before the kt-boundary barrier
// Per-wave ledger: 2 gld16/phase, 8 outstanding max; each wait retires
// exactly the halves the NEXT reads need, and the following s_barrier
// publishes them to all waves. Last K-tile peeled with one vmcnt(0) drain.
// XOR granule swizzle (source pre-swizzled, LDS linear, reads ^(row&7))
// identical to the proven 128x128 kernel (measured 0 bank conflicts).
__global__ __launch_bounds__(512, 2) void k_qkv_gemm(
    const u16* __restrict__ xb, const u16* __restrict__ wt,
    const float* __restrict__ bias,
    u16* __restrict__ qb, u16* __restrict__ kbuf, u16* __restrict__ vt) {
  __shared__ __align__(16) u16 Ab[2][256 * 64];   // 2 x 32 KB
  __shared__ __align__(16) u16 Bb[2][256 * 64];   // 2 x 32 KB

  const int t    = threadIdx.x;
  const int wid  = t >> 6;
  const int lane = t & 63;
  const int m    = lane & 15;
  const int quad = lane >> 4;
  const int wm   = wid >> 2;          // 0..1 : 128-row panel
  const int wn   = wid & 3;           // 0..3 : 64-col panel

  const int rp   = blockIdx.x & 15;   // 16 row panels
  const int cp   = blockIdx.x >> 4;   // 12 col panels
  const int row0 = rp * 256;
  const int col0 = cp * 256;

  // staging addressing: thread t -> 16B granule gs of row (base + t>>3);
  // gs = (t&7) ^ ((t>>3)&7) pre-applies the LDS read swizzle at the source.
  const int trA = t >> 3;                         // 0..63
  const int gs  = (t & 7) ^ (trA & 7);
  const int rB0 = ((t >> 8) & 1) * 64 + (trA & 31);
  const u16* agp = xb + (size_t)(row0 + trA) * 1024 + gs * 8;
  const u16* bgp = wt + (size_t)(col0 + rB0) * 1024 + gs * 8;
  const int ldsArow = wid * 8;                        // wave-uniform
  const int ldsBrow = (wid >> 2) * 64 + (wid & 3) * 8;

  // fragment-read swizzled granule offsets (row r has r&7 == m&7)
  const int sw0 = (quad ^ (m & 7)) * 8;        // kk = 0
  const int sw1 = ((4 + quad) ^ (m & 7)) * 8;  // kk = 1

  f32x4 acc[8][4];
  const f32x4 zf = {0.f, 0.f, 0.f, 0.f};
#pragma unroll
  for (int i = 0; i < 8; ++i)
#pragma unroll
    for (int j = 0; j < 4; ++j) acc[i][j] = zf;

  // prologue: stage K-tile 0 (all 4 halves of A and B) into buf 0, drain once
  gld16(agp,          &Ab[0][(  0 + ldsArow) * 64]);   // A-hs0
  gld16(agp + 131072, &Ab[0][(128 + ldsArow) * 64]);
  gld16(agp +  65536, &Ab[0][( 64 + ldsArow) * 64]);   // A-hs1
  gld16(agp + 196608, &Ab[0][(192 + ldsArow) * 64]);
  gld16(bgp,          &Bb[0][(  0 + ldsBrow) * 64]);   // B-hs0
  gld16(bgp + 131072, &Bb[0][(128 + ldsBrow) * 64]);
  gld16(bgp +  32768, &Bb[0][( 32 + ldsBrow) * 64]);   // B-hs1
  gld16(bgp + 163840, &Bb[0][(160 + ldsBrow) * 64]);
  asm volatile("s_waitcnt vmcnt(0)" ::: "memory");
  BARSB();

  bf16x8 a[4][2], b0[2][2], b1[2][2];

#define RD_A(H)                                                         \
  _Pragma("unroll") for (int mf = 0; mf < 4; ++mf) {                    \
    const u16* r_ = cA + (wm * 128 + (H) * 64 + mf * 16 + m) * 64;      \
    a[mf][0] = *(const bf16x8*)(r_ + sw0);                              \
    a[mf][1] = *(const bf16x8*)(r_ + sw1);                              \
  }
#define RD_B(H, BR)                                                     \
  _Pragma("unroll") for (int nf = 0; nf < 2; ++nf) {                    \
    const u16* r_ = cB + (wn * 64 + (H) * 32 + nf * 16 + m) * 64;       \
    BR[nf][0] = *(const bf16x8*)(r_ + sw0);                             \
    BR[nf][1] = *(const bf16x8*)(r_ + sw1);                             \
  }
#define MFMA_Q(MB, NB, BR)                                              \
  __builtin_amdgcn_s_setprio(1);                                        \
  _Pragma("unroll") for (int mf = 0; mf < 4; ++mf)                      \
    _Pragma("unroll") for (int nf = 0; nf < 2; ++nf) {                  \
      acc[(MB) + mf][(NB) + nf] = __builtin_amdgcn_mfma_f32_16x16x32_bf16( \
          a[mf][0], BR[nf][0], acc[(MB) + mf][(NB) + nf], 0, 0, 0);     \
      acc[(MB) + mf][(NB) + nf] = __builtin_amdgcn_mfma_f32_16x16x32_bf16( \
          a[mf][1], BR[nf][1], acc[(MB) + mf][(NB) + nf], 0, 0, 0);     \
    }                                                                   \
  __builtin_amdgcn_s_setprio(0);

  for (int kt = 0; kt < 15; ++kt) {
    const u16* cA = &Ab[kt & 1][0];
    const u16* cB = &Bb[kt & 1][0];
    u16* nA = &Ab[(kt + 1) & 1][0];
    u16* nB = &Bb[(kt + 1) & 1][0];
    const int kn = (kt + 1) * 64;

    // -------- phase 1
    RD_A(0)
    RD_B(0, b0)
    gld16(agp + kn,          nA + (  0 + ldsArow) * 64);   // A-hs0'
    gld16(agp + kn + 131072, nA + (128 + ldsArow) * 64);
    BARSB();
    MFMA_Q(0, 0, b0)
    asm volatile("s_waitcnt vmcnt(2)" ::: "memory");  // A-hs1,B-hs1 of kt land
    BARSB();

    // -------- phase 2
    RD_B(1, b1)
    gld16(bgp + kn,          nB + (  0 + ldsBrow) * 64);   // B-hs0'
    gld16(bgp + kn + 131072, nB + (128 + ldsBrow) * 64);
    BARSB();
    MFMA_Q(0, 2, b1)
    BARSB();

    // -------- phase 3
    RD_A(1)
    gld16(agp + kn +  65536, nA + ( 64 + ldsArow) * 64);   // A-hs1'
    gld16(agp + kn + 196608, nA + (192 + ldsArow) * 64);
    BARSB();
    MFMA_Q(4, 2, b1)
    BARSB();

    // -------- phase 4
    gld16(bgp + kn +  32768, nB + ( 32 + ldsBrow) * 64);   // B-hs1'
    gld16(bgp + kn + 163840, nB + (160 + ldsBrow) * 64);
    BARSB();
    MFMA_Q(4, 0, b0)
    asm volatile("s_waitcnt vmcnt(4)" ::: "memory");  // A-hs0',B-hs0' land
    BARSB();
  }

  // -------- peeled K-tile 15 (buf 1): drain once, no staging, no barriers
  asm volatile("s_waitcnt vmcnt(0)" ::: "memory");
  __builtin_amdgcn_s_barrier();
  __builtin_amdgcn_sched_barrier(0);
  {
    const u16* cA = &Ab[1][0];
    const u16* cB = &Bb[1][0];
    RD_A(0)
    RD_B(0, b0)
    RD_B(1, b1)
    MFMA_Q(0, 0, b0)
    MFMA_Q(0, 2, b1)
    RD_A(1)
    MFMA_Q(4, 2, b1)
    MFMA_Q(4, 0, b0)
  }

  // Epilogue. C row R = row0+wm*128+mt*16+quad*4+rg ; col = col0+wn*64+nt*16+m
  const int sec = col0 >> 10;       // uniform per block: 0=Q 1=K 2=V
#pragma unroll
  for (int nt = 0; nt < 4; ++nt) {
    const int Cc = col0 + wn * 64 + nt * 16 + m;
    const float bv = bias[Cc];
    const int c = Cc & 1023;
    const int h = c >> 6;
    const int d = c & 63;
#pragma unroll
    for (int mt = 0; mt < 8; ++mt) {
      const int Rbase = row0 + wm * 128 + mt * 16 + quad * 4;
      const int bb = Rbase >> 11;
      const int t0 = Rbase & 2047;
      const int bh = bb * HEADS + h;
      if (sec == 0) {
#pragma unroll
        for (int rg = 0; rg < 4; ++rg) {
          float v = (acc[mt][nt][rg] + bv) * 0.125f;   // fold 1/sqrt(64)
          qb[(size_t)(bh * TSEQ + t0 + rg) * HDIM + d] = f2bf(v);
        }
      } else if (sec == 1) {
#pragma unroll
        for (int rg = 0; rg < 4; ++rg) {
          float v = acc[mt][nt][rg] + bv;
          kbuf[(size_t)(bh * TSEQ + t0 + rg) * HDIM + d] = f2bf(v);
        }
      } else {
        ushort4 pk;
        pk.x = f2bf(acc[mt][nt][0] + bv);
        pk.y = f2bf(acc[mt][nt][1] + bv);
        pk.z = f2bf(acc[mt][nt][2] + bv);
        pk.w = f2bf(acc[mt][nt][3] + bv);
        *(ushort4*)(vt + (size_t)(bh * HDIM + d) * TSEQ + t0) = pk;
      }
    }
  }
#undef RD_A
#undef RD_B
#undef MFMA_Q
}

// ---------------------------------------------------------------------------
// Flash attention v4 (R1-proven best): block-cooperative K/V staging.
// 3 blocks/CU, 1024-block grid: 768 resident + 256 queued for dynamic load
// balance of the triangular workload (R3/R4: 4/CU static residency regressed).
__global__ __launch_bounds__(256, 3) void k_attn(
    const u16* __restrict__ qb, const u16* __restrict__ kbuf,
    const u16* __restrict__ vt, float* __restrict__ out) {
  __shared__ __align__(16) u16 Kb[2][4096];   // [buf][row*64 + swizzled col]
  __shared__ __align__(16) u16 Vb[2][4096];
  __shared__ __align__(16) u16 pt[4][16 * 72];

  const int t     = threadIdx.x;
  const int wv    = t >> 6;
  const int lane  = t & 63;
  const int m     = lane & 15;
  const int quad  = lane >> 4;
  const int bh    = blockIdx.x & 31;          // bh-fast
  const int qtg   = 31 - (blockIdx.x >> 5);   // long blocks dispatch first
  const int qbase = (qtg * 4 + wv) * 16;
  const int nkt   = qtg + 1;                  // SAME for all 4 waves

  u16* pw = &pt[wv][0];

  // Q fragments (B-operand of S^T), registers for the whole key loop
  const u16* qrow = qb + ((size_t)bh * TSEQ + qbase + m) * HDIM + quad * 8;
  bf16x8 aq0 = *(const bf16x8*)(qrow);
  bf16x8 aq1 = *(const bf16x8*)(qrow + 32);

  // DMA source pointers: wave wv stages rows [wv*16, wv*16+16) of each tile.
  const int sr = wv * 16 + (lane >> 3);
  const int gsk = (lane & 7) ^ (sr & 7);
  const u16* kg = kbuf + ((size_t)bh * TSEQ + sr) * HDIM + gsk * 8;
  const u16* vg = vt + ((size_t)bh * HDIM + sr) * TSEQ + gsk * 8;
  u16* klds = &Kb[0][wv * 16 * 64];   // wave-uniform; HW adds lane*16B
  u16* vlds = &Vb[0][wv * 16 * 64];

  // fragment-read swizzled granule offsets (row r has r&7 == m&7)
  const int swL = (quad ^ (m & 7)) * 8;        // logical granule quad
  const int swH = ((quad + 4) ^ (m & 7)) * 8;  // logical granule quad+4

  f32x4 o[4];
  const f32x4 zf = {0.f, 0.f, 0.f, 0.f};
  for (int nt = 0; nt < 4; ++nt) o[nt] = zf;
  float rsum = 0.f;
  const int qi = qbase + m;            // this lane's q row

  // preload tile 0 into buffer 0
  gld16(kg,             klds);
  gld16(kg + 8 * HDIM,  klds + 8 * 64);
  gld16(vg,             vlds);
  gld16(vg + 8 * TSEQ,  vlds + 8 * 64);
  __syncthreads();                     // vmcnt(0) drain + barrier

  for (int kt = 0; kt < nkt; ++kt) {
    const int b = kt & 1;
    const u16* kb0 = &Kb[b][0];
    const u16* vb0 = &Vb[b][0];

    // S^T tile: A = K rows (from LDS), B = Q (registers)
    f32x4 s[4];
    for (int nt = 0; nt < 4; ++nt) s[nt] = zf;
#pragma unroll
    for (int nt = 0; nt < 4; ++nt) {
      bf16x8 kf = *(const bf16x8*)(kb0 + (nt * 16 + m) * 64 + swL);
      s[nt] = __builtin_amdgcn_mfma_f32_16x16x32_bf16(kf, aq0, s[nt], 0, 0, 0);
    }
#pragma unroll
    for (int nt = 0; nt < 4; ++nt) {
      bf16x8 kf = *(const bf16x8*)(kb0 + (nt * 16 + m) * 64 + swH);
      s[nt] = __builtin_amdgcn_mfma_f32_16x16x32_bf16(kf, aq1, s[nt], 0, 0, 0);
    }

    // V fragments for this tile (read BEFORE issuing next DMA)
    bf16x8 vfL[4], vfH[4];
#pragma unroll
    for (int nt = 0; nt < 4; ++nt) {
      vfL[nt] = *(const bf16x8*)(vb0 + (nt * 16 + m) * 64 + swL);
      vfH[nt] = *(const bf16x8*)(vb0 + (nt * 16 + m) * 64 + swH);
    }

    // DMA tile kt+1 into the other buffer (covered by exp/P/PV below)
    if (kt + 1 < nkt) {
      const int nb = (kt + 1) & 1;
      const u16* kgn = kg + (size_t)(kt + 1) * 64 * HDIM;
      const u16* vgn = vg + (kt + 1) * 64;
      u16* kl = &Kb[nb][wv * 16 * 64];
      u16* vl = &Vb[nb][wv * 16 * 64];
      gld16(kgn,            kl);
      gld16(kgn + 8 * HDIM, kl + 8 * 64);
      gld16(vgn,            vl);
      gld16(vgn + 8 * TSEQ, vl + 8 * 64);
    }

    // causal mask: key kj = kt*64 + nt*16 + quad*4 + rg vs q row qi
    if (kt == nkt - 1) {
      const int kb = kt * 64 + quad * 4;
#pragma unroll
      for (int nt = 0; nt < 4; ++nt)
#pragma unroll
        for (int rg = 0; rg < 4; ++rg)
          if (kb + nt * 16 + rg > qi) s[nt][rg] = -1e30f;
    }

    // p = exp(s); per-lane scalar row-sum; pack 4 keys -> one b64 write
#pragma unroll
    for (int nt = 0; nt < 4; ++nt) {
      float p0 = __expf(s[nt][0]), p1 = __expf(s[nt][1]);
      float p2 = __expf(s[nt][2]), p3 = __expf(s[nt][3]);
      rsum += (p0 + p1) + (p2 + p3);
      ushort4 pk = {f2bf(p0), f2bf(p1), f2bf(p2), f2bf(p3)};
      *(ushort4*)(pw + m * 72 + nt * 16 + quad * 4) = pk;
    }
    // P: C-layout -> B-operand layout
    bf16x8 bp0 = *(const bf16x8*)(pw + m * 72 + quad * 8);
    bf16x8 bp1 = *(const bf16x8*)(pw + m * 72 + 32 + quad * 8);

    // O^T += V^T * P^T
#pragma unroll
    for (int nt = 0; nt < 4; ++nt)
      o[nt] = __builtin_amdgcn_mfma_f32_16x16x32_bf16(vfL[nt], bp0, o[nt], 0, 0, 0);
#pragma unroll
    for (int nt = 0; nt < 4; ++nt)
      o[nt] = __builtin_amdgcn_mfma_f32_16x16x32_bf16(vfH[nt], bp1, o[nt], 0, 0, 0);

    __syncthreads();   // all waves done with buf b; DMA for kt+1 drained
  }

  // l reduction: lanes {m, m+16, m+32, m+48} hold the same q row
  rsum += __shfl_xor(rsum, 16);
  rsum += __shfl_xor(rsum, 32);
  const float inv = 1.0f / rsum;

  // epilogue: O^T C-layout -> out[b][t][h*64 + nt*16 + quad*4 + rg], float4
  const int bb = bh >> 4;
  const int h  = bh & 15;
  float* ob = out + ((size_t)(bb * TSEQ + qi) * NEMBD + h * HDIM + quad * 4);
#pragma unroll
  for (int nt = 0; nt < 4; ++nt) {
    float4 st;
    st.x = o[nt][0] * inv; st.y = o[nt][1] * inv;
    st.z = o[nt][2] * inv; st.w = o[nt][3] * inv;
    *(float4*)(ob + nt * 16) = st;
  }
}

// ---------------------------------------------------------------------------
extern "C" void kernel_launch(void* const* d_in, const int* in_sizes, int n_in,
                              void* d_out, int out_size, void* d_ws, size_t ws_size,
                              hipStream_t stream) {
  (void)in_sizes; (void)n_in; (void)out_size; (void)ws_size;
  const float* x    = (const float*)d_in[0];
  const float* W    = (const float*)d_in[1];
  const float* bqkv = (const float*)d_in[2];
  float* out = (float*)d_out;

  // ws layout (u16 elements): qb | kbuf | vt | xb | wt  -> ~38 MB total
  u16* ws   = (u16*)d_ws;
  u16* qb   = ws;                       // 2*16*2048*64 = 4194304
  u16* kbuf = ws + 4194304;
  u16* vt   = ws + 2 * 4194304;
  u16* xb   = ws + 3 * 4194304;         // 4096*1024 = 4194304
  u16* wt   = ws + 4 * 4194304;         // 3072*1024 = 3145728

  hipLaunchKernelGGL(k_prep, dim3(7168), dim3(256), 0, stream, x, xb, W, wt);
  hipLaunchKernelGGL(k_qkv_gemm, dim3(192), dim3(512), 0, stream,
                     xb, wt, bqkv, qb, kbuf, vt);
  hipLaunchKernelGGL(k_attn, dim3(1024), dim3(256), 0, stream,
                     qb, kbuf, vt, out);
}